// Round 1
// baseline (403.115 us; speedup 1.0000x reference)
//
#include <hip/hip_runtime.h>
#include <hip/hip_bf16.h>
#include <stdint.h>

#define EMBED 1024
#define HEADS 16
#define HDIM 64
#define SEQ 2048
#define BATCH 2
#define MTOT (BATCH*SEQ)   // 4096
#define KDIM EMBED         // 1024
#define HALFW 128

typedef __attribute__((ext_vector_type(8))) short short8;
typedef __attribute__((ext_vector_type(4))) float floatx4;

__device__ __forceinline__ ushort f2bf(float f){
  uint32_t x = __float_as_uint(f);
  x += 0x7fffu + ((x >> 16) & 1u);   // RNE
  return (ushort)(x >> 16);
}
__device__ __forceinline__ float bflo(uint32_t w){ return __uint_as_float(w << 16); }
__device__ __forceinline__ float bfhi(uint32_t w){ return __uint_as_float(w & 0xffff0000u); }

__device__ __forceinline__ void gload16(const ushort* g, ushort* l){
  __builtin_amdgcn_global_load_lds(
      (__attribute__((address_space(1))) void*)(void*)g,
      (__attribute__((address_space(3))) void*)l, 16, 0, 0);
}

// ---------------- cast f32 -> bf16 ----------------
__global__ void cast_f32_bf16(const float* __restrict__ src, ushort* __restrict__ dst, int n){
  int i = (blockIdx.x * blockDim.x + threadIdx.x) * 4;
  if (i < n){
    float4 v = *reinterpret_cast<const float4*>(src + i);
    ushort4 o;
    o.x = f2bf(v.x); o.y = f2bf(v.y); o.z = f2bf(v.z); o.w = f2bf(v.w);
    *reinterpret_cast<ushort4*>(dst + i) = o;
  }
}

// ---------------- QKV GEMM: y = x @ W^T + b, write Q/K/V in [b,h,s,d] bf16 ----------------
__global__ __launch_bounds__(256) void gemm_qkv(
    const ushort* __restrict__ A, const ushort* __restrict__ Bw,
    const float* __restrict__ biasq, const float* __restrict__ biask, const float* __restrict__ biasv,
    ushort* __restrict__ Qo, ushort* __restrict__ Ko, ushort* __restrict__ Vo)
{
  constexpr int BM = 128, BN = 128, BK = 32;
  __shared__ __attribute__((aligned(16))) ushort As[BM*BK];
  __shared__ __attribute__((aligned(16))) ushort Bs[BN*BK];
  const int tid  = threadIdx.x;
  const int lane = tid & 63;
  const int wid  = tid >> 6;
  const int wr = wid >> 1, wc = wid & 1;
  const int m0 = blockIdx.x * BM;
  const int n0 = blockIdx.y * BN;

  floatx4 acc[4][4];
  #pragma unroll
  for (int i = 0; i < 4; ++i)
    #pragma unroll
    for (int j = 0; j < 4; ++j) acc[i][j] = (floatx4){0.f, 0.f, 0.f, 0.f};

  for (int kk = 0; kk < KDIM; kk += BK){
    if (kk) __syncthreads();
    #pragma unroll
    for (int rep = 0; rep < 2; ++rep){
      int cc = tid + rep * 256;             // chunk id 0..511, 8 bf16 each
      int row = cc >> 2, off = (cc & 3) * 8;
      gload16(A  + (size_t)(m0 + row) * KDIM + kk + off, &As[cc * 8]);
      gload16(Bw + (size_t)(n0 + row) * KDIM + kk + off, &Bs[cc * 8]);
    }
    __syncthreads();

    short8 af[4], bfr[4];
    const int rsel = lane & 15, ksel = (lane >> 4) * 8;
    #pragma unroll
    for (int m = 0; m < 4; ++m)
      af[m] = *reinterpret_cast<const short8*>(&As[(wr*64 + m*16 + rsel) * BK + ksel]);
    #pragma unroll
    for (int n = 0; n < 4; ++n)
      bfr[n] = *reinterpret_cast<const short8*>(&Bs[(wc*64 + n*16 + rsel) * BK + ksel]);
    #pragma unroll
    for (int m = 0; m < 4; ++m)
      #pragma unroll
      for (int n = 0; n < 4; ++n)
        acc[m][n] = __builtin_amdgcn_mfma_f32_16x16x32_bf16(af[m], bfr[n], acc[m][n], 0, 0, 0);
  }

  const int which = n0 >> 10;   // uniform per block (128 | 1024)
  const float* bias = (which == 0) ? biasq : ((which == 1) ? biask : biasv);
  ushort* dst = (which == 0) ? Qo : ((which == 1) ? Ko : Vo);
  const int nb = n0 & 1023;
  #pragma unroll
  for (int m = 0; m < 4; ++m)
    #pragma unroll
    for (int n = 0; n < 4; ++n)
      #pragma unroll
      for (int r = 0; r < 4; ++r){
        int mg = m0 + wr*64 + m*16 + (lane >> 4)*4 + r;   // 0..4095
        int ng = nb + wc*64 + n*16 + (lane & 15);          // 0..1023
        float v = acc[m][n][r] + bias[ng];
        int b = mg >> 11, s = mg & (SEQ - 1);
        int h = ng >> 6,  d = ng & 63;
        dst[(((size_t)(b*HEADS + h))*SEQ + s)*HDIM + d] = f2bf(v);
      }
}

// ---------------- output GEMM: out = ao @ Wo^T + bo (fp32 out) ----------------
__global__ __launch_bounds__(256) void gemm_out(
    const ushort* __restrict__ A, const ushort* __restrict__ Bw,
    const float* __restrict__ bias, float* __restrict__ Co)
{
  constexpr int BM = 128, BN = 128, BK = 32;
  __shared__ __attribute__((aligned(16))) ushort As[BM*BK];
  __shared__ __attribute__((aligned(16))) ushort Bs[BN*BK];
  const int tid  = threadIdx.x;
  const int lane = tid & 63;
  const int wid  = tid >> 6;
  const int wr = wid >> 1, wc = wid & 1;
  const int m0 = blockIdx.x * BM;
  const int n0 = blockIdx.y * BN;

  floatx4 acc[4][4];
  #pragma unroll
  for (int i = 0; i < 4; ++i)
    #pragma unroll
    for (int j = 0; j < 4; ++j) acc[i][j] = (floatx4){0.f, 0.f, 0.f, 0.f};

  for (int kk = 0; kk < KDIM; kk += BK){
    if (kk) __syncthreads();
    #pragma unroll
    for (int rep = 0; rep < 2; ++rep){
      int cc = tid + rep * 256;
      int row = cc >> 2, off = (cc & 3) * 8;
      gload16(A  + (size_t)(m0 + row) * KDIM + kk + off, &As[cc * 8]);
      gload16(Bw + (size_t)(n0 + row) * KDIM + kk + off, &Bs[cc * 8]);
    }
    __syncthreads();

    short8 af[4], bfr[4];
    const int rsel = lane & 15, ksel = (lane >> 4) * 8;
    #pragma unroll
    for (int m = 0; m < 4; ++m)
      af[m] = *reinterpret_cast<const short8*>(&As[(wr*64 + m*16 + rsel) * BK + ksel]);
    #pragma unroll
    for (int n = 0; n < 4; ++n)
      bfr[n] = *reinterpret_cast<const short8*>(&Bs[(wc*64 + n*16 + rsel) * BK + ksel]);
    #pragma unroll
    for (int m = 0; m < 4; ++m)
      #pragma unroll
      for (int n = 0; n < 4; ++n)
        acc[m][n] = __builtin_amdgcn_mfma_f32_16x16x32_bf16(af[m], bfr[n], acc[m][n], 0, 0, 0);
  }

  #pragma unroll
  for (int m = 0; m < 4; ++m)
    #pragma unroll
    for (int n = 0; n < 4; ++n)
      #pragma unroll
      for (int r = 0; r < 4; ++r){
        int mg = m0 + wr*64 + m*16 + (lane >> 4)*4 + r;
        int ng = n0 + wc*64 + n*16 + (lane & 15);
        Co[(size_t)mg * EMBED + ng] = acc[m][n][r] + bias[ng];
      }
}

// ---------------- local attention: scores + softmax + attn write + PV ----------------
__global__ __launch_bounds__(256) void attn_kernel(
    const ushort* __restrict__ Qb, const ushort* __restrict__ Kb, const ushort* __restrict__ Vb,
    float* __restrict__ attnp, ushort* __restrict__ ao)
{
  constexpr int TQ = 16;
  constexpr int CMAX = 288;
  constexpr int KPAD = 72;   // +8 pad: breaks the 128B-row-stride bank conflict
  __shared__ __attribute__((aligned(16))) float  Qs[TQ][HDIM];
  __shared__ __attribute__((aligned(16))) ushort Ks[CMAX][KPAD];
  __shared__ __attribute__((aligned(16))) float  Ss[TQ][CMAX];
  __shared__ float rowinv[TQ];

  const int tid = threadIdx.x;
  const int qt = blockIdx.x;     // 0..127
  const int bh = blockIdx.y;     // 0..31
  const int q0 = qt * TQ;
  const int c0 = max(0, q0 - HALFW);
  const int c1 = min(SEQ, q0 + TQ + HALFW);  // exclusive
  const int nc = c1 - c0;                    // <= 272

  const ushort* Qg = Qb + ((size_t)bh * SEQ + q0) * HDIM;
  const ushort* Kg = Kb + ((size_t)bh * SEQ + c0) * HDIM;
  const ushort* Vg = Vb + ((size_t)bh * SEQ) * HDIM;

  // stage Q (bf16 -> f32)
  if (tid < 128){
    int row = tid >> 3, off = (tid & 7) * 8;
    uint4 v = *reinterpret_cast<const uint4*>(Qg + row * HDIM + off);
    float* qp = &Qs[row][off];
    qp[0] = bflo(v.x); qp[1] = bfhi(v.x); qp[2] = bflo(v.y); qp[3] = bfhi(v.y);
    qp[4] = bflo(v.z); qp[5] = bfhi(v.z); qp[6] = bflo(v.w); qp[7] = bfhi(v.w);
  }
  // stage K window (bf16 raw)
  for (int ch = tid; ch < nc * 8; ch += 256){
    int row = ch >> 3, off = (ch & 7) * 8;
    *reinterpret_cast<uint4*>(&Ks[row][off]) =
        *reinterpret_cast<const uint4*>(Kg + row * HDIM + off);
  }
  __syncthreads();

  // scores
  const int r  = tid >> 4;   // 0..15
  const int lc = tid & 15;
  const int q  = q0 + r;
  for (int j = lc; j < nc; j += 16){
    int c = c0 + j;
    float s;
    if (c < q - HALFW || c > q + HALFW){
      s = -1e30f;
    } else {
      float a = 0.f;
      #pragma unroll
      for (int dc = 0; dc < 8; ++dc){
        uint4 kv = *reinterpret_cast<const uint4*>(&Ks[j][dc * 8]);
        const float* qp = &Qs[r][dc * 8];
        a += qp[0]*bflo(kv.x) + qp[1]*bfhi(kv.x)
           + qp[2]*bflo(kv.y) + qp[3]*bfhi(kv.y)
           + qp[4]*bflo(kv.z) + qp[5]*bfhi(kv.z)
           + qp[6]*bflo(kv.w) + qp[7]*bfhi(kv.w);
      }
      s = a * 0.125f;   // 1/sqrt(64)
    }
    Ss[r][j] = s;
  }
  __syncthreads();

  // softmax over row r (16 threads per row, lanes stay in one 16-group)
  float mx = -1e30f;
  for (int j = lc; j < nc; j += 16) mx = fmaxf(mx, Ss[r][j]);
  #pragma unroll
  for (int o = 1; o < 16; o <<= 1) mx = fmaxf(mx, __shfl_xor(mx, o, 64));
  float sum = 0.f;
  for (int j = lc; j < nc; j += 16){
    float p = __expf(Ss[r][j] - mx);   // masked entries underflow to exactly 0
    Ss[r][j] = p;
    sum += p;
  }
  #pragma unroll
  for (int o = 1; o < 16; o <<= 1) sum += __shfl_xor(sum, o, 64);
  if (lc == 0) rowinv[r] = 1.f / sum;
  __syncthreads();

  // write attn window (rest of the row is zero via memset)
  for (int rr = 0; rr < TQ; ++rr){
    float inv = rowinv[rr];
    float* dst = attnp + ((size_t)bh * SEQ + (q0 + rr)) * SEQ + c0;
    for (int j = tid; j < nc; j += 256) dst[j] = Ss[rr][j] * inv;
  }

  // PV: wave w handles rows w*4..w*4+3, lane = output dim d
  const int w = tid >> 6;
  const int d = tid & 63;
  float acc[4] = {0.f, 0.f, 0.f, 0.f};
  for (int j = 0; j < nc; ++j){
    float v = __uint_as_float((uint32_t)Vg[((size_t)(c0 + j)) * HDIM + d] << 16);
    #pragma unroll
    for (int i = 0; i < 4; ++i) acc[i] += Ss[w*4 + i][j] * v;
  }
  const int b = bh >> 4, h = bh & 15;
  #pragma unroll
  for (int i = 0; i < 4; ++i){
    int qq = q0 + w*4 + i;
    float val = acc[i] * rowinv[w*4 + i];
    ao[((size_t)(b * SEQ + qq)) * EMBED + h * HDIM + d] = f2bf(val);
  }
}

extern "C" void kernel_launch(void* const* d_in, const int* in_sizes, int n_in,
                              void* d_out, int out_size, void* d_ws, size_t ws_size,
                              hipStream_t stream)
{
  const float* x  = (const float*)d_in[0];
  const float* Wq = (const float*)d_in[1];
  const float* bq = (const float*)d_in[2];
  const float* Wk = (const float*)d_in[3];
  const float* bk = (const float*)d_in[4];
  const float* Wv = (const float*)d_in[5];
  const float* bv = (const float*)d_in[6];
  const float* Wo = (const float*)d_in[7];
  const float* bo = (const float*)d_in[8];

  char* ws = (char*)d_ws;
  ushort* xb   = (ushort*)(ws);                 // x bf16           [4096][1024]
  ushort* wqkv = (ushort*)(ws + 8388608);       // Wq|Wk|Wv bf16    [3072][1024]
  ushort* wo   = (ushort*)(ws + 14680064);      // Wo bf16          [1024][1024]
  ushort* Qb   = (ushort*)(ws + 16777216);      // Q bf16 [b,h,s,d]
  ushort* Kb   = (ushort*)(ws + 25165824);      // K bf16
  ushort* Vb   = (ushort*)(ws + 33554432);      // V bf16
  ushort* ao   = (ushort*)(ws + 41943040);      // attn out bf16 [b,s,e]

  float* outp  = (float*)d_out;                           // [2,2048,1024]
  float* attnp = outp + (size_t)MTOT * EMBED;             // [2,16,2048,2048]

  // zero the attention matrix (everything outside the window must be 0)
  hipMemsetAsync(attnp, 0, (size_t)BATCH * HEADS * SEQ * SEQ * sizeof(float), stream);

  cast_f32_bf16<<<4096, 256, 0, stream>>>(x,  xb,             4194304);
  cast_f32_bf16<<<1024, 256, 0, stream>>>(Wq, wqkv,           1048576);
  cast_f32_bf16<<<1024, 256, 0, stream>>>(Wk, wqkv + 1048576, 1048576);
  cast_f32_bf16<<<1024, 256, 0, stream>>>(Wv, wqkv + 2097152, 1048576);
  cast_f32_bf16<<<1024, 256, 0, stream>>>(Wo, wo,             1048576);

  gemm_qkv<<<dim3(32, 24), 256, 0, stream>>>(xb, wqkv, bq, bk, bv, Qb, Kb, Vb);
  attn_kernel<<<dim3(128, 32), 256, 0, stream>>>(Qb, Kb, Vb, attnp, ao);
  gemm_out<<<dim3(32, 8), 256, 0, stream>>>(ao, wo, bo, outp);
}

// Round 3
// 354.659 us; speedup vs baseline: 1.1366x; 1.1366x over previous
//
#include <hip/hip_runtime.h>
#include <hip/hip_bf16.h>
#include <stdint.h>

#define EMBED 1024
#define HEADS 16
#define HDIM 64
#define SEQ 2048
#define BATCH 2
#define MTOT (BATCH*SEQ)   // 4096
#define KDIM EMBED         // 1024
#define HALFW 128

typedef __attribute__((ext_vector_type(8))) short short8;
typedef __attribute__((ext_vector_type(4))) float floatx4;

__device__ __forceinline__ ushort f2bf(float f){
  uint32_t x = __float_as_uint(f);
  x += 0x7fffu + ((x >> 16) & 1u);   // RNE
  return (ushort)(x >> 16);
}
__device__ __forceinline__ float bflo(uint32_t w){ return __uint_as_float(w << 16); }
__device__ __forceinline__ float bfhi(uint32_t w){ return __uint_as_float(w & 0xffff0000u); }

__device__ __forceinline__ void gload16(const ushort* g, ushort* l){
  __builtin_amdgcn_global_load_lds(
      (__attribute__((address_space(1))) void*)(void*)g,
      (__attribute__((address_space(3))) void*)l, 16, 0, 0);
}

// ---------------- cast f32 -> bf16 ----------------
__global__ void cast_f32_bf16(const float* __restrict__ src, ushort* __restrict__ dst, int n){
  int i = (blockIdx.x * blockDim.x + threadIdx.x) * 4;
  if (i < n){
    float4 v = *reinterpret_cast<const float4*>(src + i);
    ushort4 o;
    o.x = f2bf(v.x); o.y = f2bf(v.y); o.z = f2bf(v.z); o.w = f2bf(v.w);
    *reinterpret_cast<ushort4*>(dst + i) = o;
  }
}

// ---------------- QKV GEMM: y = x @ W^T + b, write Q/K/V in [b,h,s,d] bf16 ----------------
__global__ __launch_bounds__(256) void gemm_qkv(
    const ushort* __restrict__ A, const ushort* __restrict__ Bw,
    const float* __restrict__ biasq, const float* __restrict__ biask, const float* __restrict__ biasv,
    ushort* __restrict__ Qo, ushort* __restrict__ Ko, ushort* __restrict__ Vo)
{
  constexpr int BM = 128, BN = 128, BK = 32;
  __shared__ __attribute__((aligned(16))) ushort As[BM*BK];
  __shared__ __attribute__((aligned(16))) ushort Bs[BN*BK];
  const int tid  = threadIdx.x;
  const int lane = tid & 63;
  const int wid  = tid >> 6;
  const int wr = wid >> 1, wc = wid & 1;
  const int m0 = blockIdx.x * BM;
  const int n0 = blockIdx.y * BN;

  floatx4 acc[4][4];
  #pragma unroll
  for (int i = 0; i < 4; ++i)
    #pragma unroll
    for (int j = 0; j < 4; ++j) acc[i][j] = (floatx4){0.f, 0.f, 0.f, 0.f};

  for (int kk = 0; kk < KDIM; kk += BK){
    if (kk) __syncthreads();
    #pragma unroll
    for (int rep = 0; rep < 2; ++rep){
      int cc = tid + rep * 256;             // chunk id 0..511, 8 bf16 each
      int row = cc >> 2, off = (cc & 3) * 8;
      gload16(A  + (size_t)(m0 + row) * KDIM + kk + off, &As[cc * 8]);
      gload16(Bw + (size_t)(n0 + row) * KDIM + kk + off, &Bs[cc * 8]);
    }
    __syncthreads();

    short8 af[4], bfr[4];
    const int rsel = lane & 15, ksel = (lane >> 4) * 8;
    #pragma unroll
    for (int m = 0; m < 4; ++m)
      af[m] = *reinterpret_cast<const short8*>(&As[(wr*64 + m*16 + rsel) * BK + ksel]);
    #pragma unroll
    for (int n = 0; n < 4; ++n)
      bfr[n] = *reinterpret_cast<const short8*>(&Bs[(wc*64 + n*16 + rsel) * BK + ksel]);
    #pragma unroll
    for (int m = 0; m < 4; ++m)
      #pragma unroll
      for (int n = 0; n < 4; ++n)
        acc[m][n] = __builtin_amdgcn_mfma_f32_16x16x32_bf16(af[m], bfr[n], acc[m][n], 0, 0, 0);
  }

  const int which = n0 >> 10;   // uniform per block (128 | 1024)
  const float* bias = (which == 0) ? biasq : ((which == 1) ? biask : biasv);
  ushort* dst = (which == 0) ? Qo : ((which == 1) ? Ko : Vo);
  const int nb = n0 & 1023;
  #pragma unroll
  for (int m = 0; m < 4; ++m)
    #pragma unroll
    for (int n = 0; n < 4; ++n)
      #pragma unroll
      for (int r = 0; r < 4; ++r){
        int mg = m0 + wr*64 + m*16 + (lane >> 4)*4 + r;   // 0..4095
        int ng = nb + wc*64 + n*16 + (lane & 15);          // 0..1023
        float v = acc[m][n][r] + bias[ng];
        int b = mg >> 11, s = mg & (SEQ - 1);
        int h = ng >> 6,  d = ng & 63;
        dst[(((size_t)(b*HEADS + h))*SEQ + s)*HDIM + d] = f2bf(v);
      }
}

// ---------------- output GEMM: out = ao @ Wo^T + bo (fp32 out) ----------------
__global__ __launch_bounds__(256) void gemm_out(
    const ushort* __restrict__ A, const ushort* __restrict__ Bw,
    const float* __restrict__ bias, float* __restrict__ Co)
{
  constexpr int BM = 128, BN = 128, BK = 32;
  __shared__ __attribute__((aligned(16))) ushort As[BM*BK];
  __shared__ __attribute__((aligned(16))) ushort Bs[BN*BK];
  const int tid  = threadIdx.x;
  const int lane = tid & 63;
  const int wid  = tid >> 6;
  const int wr = wid >> 1, wc = wid & 1;
  const int m0 = blockIdx.x * BM;
  const int n0 = blockIdx.y * BN;

  floatx4 acc[4][4];
  #pragma unroll
  for (int i = 0; i < 4; ++i)
    #pragma unroll
    for (int j = 0; j < 4; ++j) acc[i][j] = (floatx4){0.f, 0.f, 0.f, 0.f};

  for (int kk = 0; kk < KDIM; kk += BK){
    if (kk) __syncthreads();
    #pragma unroll
    for (int rep = 0; rep < 2; ++rep){
      int cc = tid + rep * 256;
      int row = cc >> 2, off = (cc & 3) * 8;
      gload16(A  + (size_t)(m0 + row) * KDIM + kk + off, &As[cc * 8]);
      gload16(Bw + (size_t)(n0 + row) * KDIM + kk + off, &Bs[cc * 8]);
    }
    __syncthreads();

    short8 af[4], bfr[4];
    const int rsel = lane & 15, ksel = (lane >> 4) * 8;
    #pragma unroll
    for (int m = 0; m < 4; ++m)
      af[m] = *reinterpret_cast<const short8*>(&As[(wr*64 + m*16 + rsel) * BK + ksel]);
    #pragma unroll
    for (int n = 0; n < 4; ++n)
      bfr[n] = *reinterpret_cast<const short8*>(&Bs[(wc*64 + n*16 + rsel) * BK + ksel]);
    #pragma unroll
    for (int m = 0; m < 4; ++m)
      #pragma unroll
      for (int n = 0; n < 4; ++n)
        acc[m][n] = __builtin_amdgcn_mfma_f32_16x16x32_bf16(af[m], bfr[n], acc[m][n], 0, 0, 0);
  }

  #pragma unroll
  for (int m = 0; m < 4; ++m)
    #pragma unroll
    for (int n = 0; n < 4; ++n)
      #pragma unroll
      for (int r = 0; r < 4; ++r){
        int mg = m0 + wr*64 + m*16 + (lane >> 4)*4 + r;
        int ng = n0 + wc*64 + n*16 + (lane & 15);
        Co[(size_t)mg * EMBED + ng] = acc[m][n][r] + bias[ng];
      }
}

// ---------------- local attention: scores + softmax + full-row attn write + PV ----------------
__global__ __launch_bounds__(256) void attn_kernel(
    const ushort* __restrict__ Qb, const ushort* __restrict__ Kb, const ushort* __restrict__ Vb,
    float* __restrict__ attnp, ushort* __restrict__ ao)
{
  constexpr int TQ = 16;
  constexpr int CMAX = 288;
  constexpr int KPAD = 72;   // +8 pad: breaks the 128B-row-stride bank conflict
  __shared__ __attribute__((aligned(16))) float  Qs[TQ][HDIM];
  __shared__ __attribute__((aligned(16))) ushort Ks[CMAX][KPAD];
  __shared__ __attribute__((aligned(16))) float  Ss[TQ][CMAX];
  __shared__ float rowinv[TQ];

  const int tid = threadIdx.x;
  const int qt = blockIdx.x;     // 0..127
  const int bh = blockIdx.y;     // 0..31
  const int q0 = qt * TQ;
  const int c0 = max(0, q0 - HALFW);
  const int c1 = min(SEQ, q0 + TQ + HALFW);  // exclusive
  const int nc = c1 - c0;                    // <= 272

  const ushort* Qg = Qb + ((size_t)bh * SEQ + q0) * HDIM;
  const ushort* Kg = Kb + ((size_t)bh * SEQ + c0) * HDIM;
  const ushort* Vg = Vb + ((size_t)bh * SEQ) * HDIM;

  // stage Q (bf16 -> f32)
  if (tid < 128){
    int row = tid >> 3, off = (tid & 7) * 8;
    uint4 v = *reinterpret_cast<const uint4*>(Qg + row * HDIM + off);
    float* qp = &Qs[row][off];
    qp[0] = bflo(v.x); qp[1] = bfhi(v.x); qp[2] = bflo(v.y); qp[3] = bfhi(v.y);
    qp[4] = bflo(v.z); qp[5] = bfhi(v.z); qp[6] = bflo(v.w); qp[7] = bfhi(v.w);
  }
  // stage K window (bf16 raw)
  for (int ch = tid; ch < nc * 8; ch += 256){
    int row = ch >> 3, off = (ch & 7) * 8;
    *reinterpret_cast<uint4*>(&Ks[row][off]) =
        *reinterpret_cast<const uint4*>(Kg + row * HDIM + off);
  }
  __syncthreads();

  // scores
  const int r  = tid >> 4;   // 0..15
  const int lc = tid & 15;
  const int q  = q0 + r;
  for (int j = lc; j < nc; j += 16){
    int c = c0 + j;
    float s;
    if (c < q - HALFW || c > q + HALFW){
      s = -1e30f;
    } else {
      float a = 0.f;
      #pragma unroll
      for (int dc = 0; dc < 8; ++dc){
        uint4 kv = *reinterpret_cast<const uint4*>(&Ks[j][dc * 8]);
        const float* qp = &Qs[r][dc * 8];
        a += qp[0]*bflo(kv.x) + qp[1]*bfhi(kv.x)
           + qp[2]*bflo(kv.y) + qp[3]*bfhi(kv.y)
           + qp[4]*bflo(kv.z) + qp[5]*bfhi(kv.z)
           + qp[6]*bflo(kv.w) + qp[7]*bfhi(kv.w);
      }
      s = a * 0.125f;   // 1/sqrt(64)
    }
    Ss[r][j] = s;
  }
  __syncthreads();

  // softmax over row r (16 threads per row, lanes stay in one 16-group)
  float mx = -1e30f;
  for (int j = lc; j < nc; j += 16) mx = fmaxf(mx, Ss[r][j]);
  #pragma unroll
  for (int o = 1; o < 16; o <<= 1) mx = fmaxf(mx, __shfl_xor(mx, o, 64));
  float sum = 0.f;
  for (int j = lc; j < nc; j += 16){
    float p = __expf(Ss[r][j] - mx);   // masked entries underflow to exactly 0
    Ss[r][j] = p;
    sum += p;
  }
  #pragma unroll
  for (int o = 1; o < 16; o <<= 1) sum += __shfl_xor(sum, o, 64);
  if (lc == 0) rowinv[r] = 1.f / sum;
  __syncthreads();

  // write FULL attn rows: zeros outside [c0,c1), softmax values inside.
  // 16 rows x 2048 f32 per block, 16B nontemporal stores, fully coalesced.
  for (int rr = 0; rr < TQ; ++rr){
    float inv = rowinv[rr];
    floatx4* dst = reinterpret_cast<floatx4*>(attnp + ((size_t)bh * SEQ + (q0 + rr)) * SEQ);
    for (int j4 = tid; j4 < SEQ / 4; j4 += 256){
      int j = j4 * 4;
      floatx4 v;
      #pragma unroll
      for (int e = 0; e < 4; ++e){
        int col = j + e;
        int jj = min(max(col - c0, 0), CMAX - 1);
        v[e] = (col >= c0 && col < c1) ? Ss[rr][jj] * inv : 0.f;
      }
      __builtin_nontemporal_store(v, &dst[j4]);
    }
  }

  // PV: wave w handles rows w*4..w*4+3, lane = output dim d
  const int w = tid >> 6;
  const int d = tid & 63;
  float acc[4] = {0.f, 0.f, 0.f, 0.f};
  for (int j = 0; j < nc; ++j){
    float v = __uint_as_float((uint32_t)Vg[((size_t)(c0 + j)) * HDIM + d] << 16);
    #pragma unroll
    for (int i = 0; i < 4; ++i) acc[i] += Ss[w*4 + i][j] * v;
  }
  const int b = bh >> 4, h = bh & 15;
  #pragma unroll
  for (int i = 0; i < 4; ++i){
    int qq = q0 + w*4 + i;
    float val = acc[i] * rowinv[w*4 + i];
    ao[((size_t)(b * SEQ + qq)) * EMBED + h * HDIM + d] = f2bf(val);
  }
}

extern "C" void kernel_launch(void* const* d_in, const int* in_sizes, int n_in,
                              void* d_out, int out_size, void* d_ws, size_t ws_size,
                              hipStream_t stream)
{
  const float* x  = (const float*)d_in[0];
  const float* Wq = (const float*)d_in[1];
  const float* bq = (const float*)d_in[2];
  const float* Wk = (const float*)d_in[3];
  const float* bk = (const float*)d_in[4];
  const float* Wv = (const float*)d_in[5];
  const float* bv = (const float*)d_in[6];
  const float* Wo = (const float*)d_in[7];
  const float* bo = (const float*)d_in[8];

  char* ws = (char*)d_ws;
  ushort* xb   = (ushort*)(ws);                 // x bf16           [4096][1024]
  ushort* wqkv = (ushort*)(ws + 8388608);       // Wq|Wk|Wv bf16    [3072][1024]
  ushort* wo   = (ushort*)(ws + 14680064);      // Wo bf16          [1024][1024]
  ushort* Qb   = (ushort*)(ws + 16777216);      // Q bf16 [b,h,s,d]
  ushort* Kb   = (ushort*)(ws + 25165824);      // K bf16
  ushort* Vb   = (ushort*)(ws + 33554432);      // V bf16
  ushort* ao   = (ushort*)(ws + 41943040);      // attn out bf16 [b,s,e]

  float* outp  = (float*)d_out;                           // [2,2048,1024]
  float* attnp = outp + (size_t)MTOT * EMBED;             // [2,16,2048,2048]

  cast_f32_bf16<<<4096, 256, 0, stream>>>(x,  xb,             4194304);
  cast_f32_bf16<<<1024, 256, 0, stream>>>(Wq, wqkv,           1048576);
  cast_f32_bf16<<<1024, 256, 0, stream>>>(Wk, wqkv + 1048576, 1048576);
  cast_f32_bf16<<<1024, 256, 0, stream>>>(Wv, wqkv + 2097152, 1048576);
  cast_f32_bf16<<<1024, 256, 0, stream>>>(Wo, wo,             1048576);

  gemm_qkv<<<dim3(32, 24), 256, 0, stream>>>(xb, wqkv, bq, bk, bv, Qb, Kb, Vb);
  attn_kernel<<<dim3(128, 32), 256, 0, stream>>>(Qb, Kb, Vb, attnp, ao);
  gemm_out<<<dim3(32, 8), 256, 0, stream>>>(ao, wo, bo, outp);
}

// Round 4
// 316.863 us; speedup vs baseline: 1.2722x; 1.1193x over previous
//
#include <hip/hip_runtime.h>
#include <hip/hip_bf16.h>
#include <stdint.h>

#define EMBED 1024
#define HEADS 16
#define HDIM 64
#define SEQ 2048
#define BATCH 2
#define MTOT (BATCH*SEQ)   // 4096
#define KDIM EMBED         // 1024
#define HALFW 128

typedef __attribute__((ext_vector_type(8))) short short8;
typedef __attribute__((ext_vector_type(4))) float floatx4;

__device__ __forceinline__ ushort f2bf(float f){
  uint32_t x = __float_as_uint(f);
  x += 0x7fffu + ((x >> 16) & 1u);   // RNE
  return (ushort)(x >> 16);
}
__device__ __forceinline__ float bflo(uint32_t w){ return __uint_as_float(w << 16); }
__device__ __forceinline__ float bfhi(uint32_t w){ return __uint_as_float(w & 0xffff0000u); }

__device__ __forceinline__ void gload16(const ushort* g, ushort* l){
  __builtin_amdgcn_global_load_lds(
      (__attribute__((address_space(1))) void*)(void*)g,
      (__attribute__((address_space(3))) void*)l, 16, 0, 0);
}

// ---------------- cast f32 -> bf16 ----------------
__global__ void cast_f32_bf16(const float* __restrict__ src, ushort* __restrict__ dst, int n){
  int i = (blockIdx.x * blockDim.x + threadIdx.x) * 4;
  if (i < n){
    float4 v = *reinterpret_cast<const float4*>(src + i);
    ushort4 o;
    o.x = f2bf(v.x); o.y = f2bf(v.y); o.z = f2bf(v.z); o.w = f2bf(v.w);
    *reinterpret_cast<ushort4*>(dst + i) = o;
  }
}

// ---------------- QKV GEMM: y = x @ W^T + b, write Q/K/V in [b,h,s,d] bf16 ----------------
__global__ __launch_bounds__(256) void gemm_qkv(
    const ushort* __restrict__ A, const ushort* __restrict__ Bw,
    const float* __restrict__ biasq, const float* __restrict__ biask, const float* __restrict__ biasv,
    ushort* __restrict__ Qo, ushort* __restrict__ Ko, ushort* __restrict__ Vo)
{
  constexpr int BM = 128, BN = 128, BK = 32;
  __shared__ __attribute__((aligned(16))) ushort As[BM*BK];
  __shared__ __attribute__((aligned(16))) ushort Bs[BN*BK];
  const int tid  = threadIdx.x;
  const int lane = tid & 63;
  const int wid  = tid >> 6;
  const int wr = wid >> 1, wc = wid & 1;
  const int m0 = blockIdx.x * BM;
  const int n0 = blockIdx.y * BN;

  floatx4 acc[4][4];
  #pragma unroll
  for (int i = 0; i < 4; ++i)
    #pragma unroll
    for (int j = 0; j < 4; ++j) acc[i][j] = (floatx4){0.f, 0.f, 0.f, 0.f};

  for (int kk = 0; kk < KDIM; kk += BK){
    if (kk) __syncthreads();
    #pragma unroll
    for (int rep = 0; rep < 2; ++rep){
      int cc = tid + rep * 256;             // chunk id 0..511, 8 bf16 each
      int row = cc >> 2, off = (cc & 3) * 8;
      gload16(A  + (size_t)(m0 + row) * KDIM + kk + off, &As[cc * 8]);
      gload16(Bw + (size_t)(n0 + row) * KDIM + kk + off, &Bs[cc * 8]);
    }
    __syncthreads();

    short8 af[4], bfr[4];
    const int rsel = lane & 15, ksel = (lane >> 4) * 8;
    #pragma unroll
    for (int m = 0; m < 4; ++m)
      af[m] = *reinterpret_cast<const short8*>(&As[(wr*64 + m*16 + rsel) * BK + ksel]);
    #pragma unroll
    for (int n = 0; n < 4; ++n)
      bfr[n] = *reinterpret_cast<const short8*>(&Bs[(wc*64 + n*16 + rsel) * BK + ksel]);
    #pragma unroll
    for (int m = 0; m < 4; ++m)
      #pragma unroll
      for (int n = 0; n < 4; ++n)
        acc[m][n] = __builtin_amdgcn_mfma_f32_16x16x32_bf16(af[m], bfr[n], acc[m][n], 0, 0, 0);
  }

  const int which = n0 >> 10;   // uniform per block (128 | 1024)
  const float* bias = (which == 0) ? biasq : ((which == 1) ? biask : biasv);
  ushort* dst = (which == 0) ? Qo : ((which == 1) ? Ko : Vo);
  const int nb = n0 & 1023;
  #pragma unroll
  for (int m = 0; m < 4; ++m)
    #pragma unroll
    for (int n = 0; n < 4; ++n)
      #pragma unroll
      for (int r = 0; r < 4; ++r){
        int mg = m0 + wr*64 + m*16 + (lane >> 4)*4 + r;   // 0..4095
        int ng = nb + wc*64 + n*16 + (lane & 15);          // 0..1023
        float v = acc[m][n][r] + bias[ng];
        int b = mg >> 11, s = mg & (SEQ - 1);
        int h = ng >> 6,  d = ng & 63;
        dst[(((size_t)(b*HEADS + h))*SEQ + s)*HDIM + d] = f2bf(v);
      }
}

// ---------------- output GEMM: out = ao @ Wo^T + bo (fp32 out) ----------------
__global__ __launch_bounds__(256) void gemm_out(
    const ushort* __restrict__ A, const ushort* __restrict__ Bw,
    const float* __restrict__ bias, float* __restrict__ Co)
{
  constexpr int BM = 128, BN = 128, BK = 32;
  __shared__ __attribute__((aligned(16))) ushort As[BM*BK];
  __shared__ __attribute__((aligned(16))) ushort Bs[BN*BK];
  const int tid  = threadIdx.x;
  const int lane = tid & 63;
  const int wid  = tid >> 6;
  const int wr = wid >> 1, wc = wid & 1;
  const int m0 = blockIdx.x * BM;
  const int n0 = blockIdx.y * BN;

  floatx4 acc[4][4];
  #pragma unroll
  for (int i = 0; i < 4; ++i)
    #pragma unroll
    for (int j = 0; j < 4; ++j) acc[i][j] = (floatx4){0.f, 0.f, 0.f, 0.f};

  for (int kk = 0; kk < KDIM; kk += BK){
    if (kk) __syncthreads();
    #pragma unroll
    for (int rep = 0; rep < 2; ++rep){
      int cc = tid + rep * 256;
      int row = cc >> 2, off = (cc & 3) * 8;
      gload16(A  + (size_t)(m0 + row) * KDIM + kk + off, &As[cc * 8]);
      gload16(Bw + (size_t)(n0 + row) * KDIM + kk + off, &Bs[cc * 8]);
    }
    __syncthreads();

    short8 af[4], bfr[4];
    const int rsel = lane & 15, ksel = (lane >> 4) * 8;
    #pragma unroll
    for (int m = 0; m < 4; ++m)
      af[m] = *reinterpret_cast<const short8*>(&As[(wr*64 + m*16 + rsel) * BK + ksel]);
    #pragma unroll
    for (int n = 0; n < 4; ++n)
      bfr[n] = *reinterpret_cast<const short8*>(&Bs[(wc*64 + n*16 + rsel) * BK + ksel]);
    #pragma unroll
    for (int m = 0; m < 4; ++m)
      #pragma unroll
      for (int n = 0; n < 4; ++n)
        acc[m][n] = __builtin_amdgcn_mfma_f32_16x16x32_bf16(af[m], bfr[n], acc[m][n], 0, 0, 0);
  }

  #pragma unroll
  for (int m = 0; m < 4; ++m)
    #pragma unroll
    for (int n = 0; n < 4; ++n)
      #pragma unroll
      for (int r = 0; r < 4; ++r){
        int mg = m0 + wr*64 + m*16 + (lane >> 4)*4 + r;
        int ng = n0 + wc*64 + n*16 + (lane & 15);
        Co[(size_t)mg * EMBED + ng] = acc[m][n][r] + bias[ng];
      }
}

// ---------------- local attention: scores + softmax + full-row attn write + PV ----------------
__global__ __launch_bounds__(256) void attn_kernel(
    const ushort* __restrict__ Qb, const ushort* __restrict__ Kb, const ushort* __restrict__ Vb,
    float* __restrict__ attnp, ushort* __restrict__ ao)
{
  constexpr int TQ = 16;
  constexpr int CMAX = 288;
  constexpr int KPAD = 72;   // +8 pad: breaks the 128B-row-stride bank conflict
  __shared__ __attribute__((aligned(16))) float  Qs[TQ][HDIM];
  __shared__ __attribute__((aligned(16))) ushort Ks[CMAX][KPAD];
  __shared__ __attribute__((aligned(16))) float  Ss[TQ][CMAX];
  __shared__ float rowinv[TQ];

  const int tid = threadIdx.x;
  const int qt = blockIdx.x;     // 0..127
  const int bh = blockIdx.y;     // 0..31
  const int q0 = qt * TQ;
  const int c0 = max(0, q0 - HALFW);
  const int c1 = min(SEQ, q0 + TQ + HALFW);  // exclusive; c0,c1 multiples of 16
  const int nc = c1 - c0;                    // <= 272

  const ushort* Qg = Qb + ((size_t)bh * SEQ + q0) * HDIM;
  const ushort* Kg = Kb + ((size_t)bh * SEQ + c0) * HDIM;
  const ushort* Vg = Vb + ((size_t)bh * SEQ) * HDIM;

  // stage Q (bf16 -> f32)
  if (tid < 128){
    int row = tid >> 3, off = (tid & 7) * 8;
    uint4 v = *reinterpret_cast<const uint4*>(Qg + row * HDIM + off);
    float* qp = &Qs[row][off];
    qp[0] = bflo(v.x); qp[1] = bfhi(v.x); qp[2] = bflo(v.y); qp[3] = bfhi(v.y);
    qp[4] = bflo(v.z); qp[5] = bfhi(v.z); qp[6] = bflo(v.w); qp[7] = bfhi(v.w);
  }
  // stage K window (bf16 raw)
  for (int ch = tid; ch < nc * 8; ch += 256){
    int row = ch >> 3, off = (ch & 7) * 8;
    *reinterpret_cast<uint4*>(&Ks[row][off]) =
        *reinterpret_cast<const uint4*>(Kg + row * HDIM + off);
  }
  __syncthreads();

  // scores
  const int r  = tid >> 4;   // 0..15
  const int lc = tid & 15;
  const int q  = q0 + r;
  for (int j = lc; j < nc; j += 16){
    int c = c0 + j;
    float s;
    if (c < q - HALFW || c > q + HALFW){
      s = -1e30f;
    } else {
      float a = 0.f;
      #pragma unroll
      for (int dc = 0; dc < 8; ++dc){
        uint4 kv = *reinterpret_cast<const uint4*>(&Ks[j][dc * 8]);
        const float* qp = &Qs[r][dc * 8];
        a += qp[0]*bflo(kv.x) + qp[1]*bfhi(kv.x)
           + qp[2]*bflo(kv.y) + qp[3]*bfhi(kv.y)
           + qp[4]*bflo(kv.z) + qp[5]*bfhi(kv.z)
           + qp[6]*bflo(kv.w) + qp[7]*bfhi(kv.w);
      }
      s = a * 0.125f;   // 1/sqrt(64)
    }
    Ss[r][j] = s;
  }
  __syncthreads();

  // softmax over row r (16 threads per row, lanes stay in one 16-group)
  float mx = -1e30f;
  for (int j = lc; j < nc; j += 16) mx = fmaxf(mx, Ss[r][j]);
  #pragma unroll
  for (int o = 1; o < 16; o <<= 1) mx = fmaxf(mx, __shfl_xor(mx, o, 64));
  float sum = 0.f;
  for (int j = lc; j < nc; j += 16){
    float p = __expf(Ss[r][j] - mx);   // masked entries underflow to exactly 0
    Ss[r][j] = p;
    sum += p;
  }
  #pragma unroll
  for (int o = 1; o < 16; o <<= 1) sum += __shfl_xor(sum, o, 64);
  if (lc == 0) rowinv[r] = 1.f / sum;
  __syncthreads();

  // write FULL attn rows. c0/c1 are multiples of 16 -> float4 chunks align with
  // the window boundary: zero chunks are pure nontemporal stores (no LDS, no
  // selects); window chunks are one aligned ds_read_b128 each.
  const int jz0 = c0 >> 2, jz1 = c1 >> 2;   // window chunk range
  const floatx4 zero4 = (floatx4){0.f, 0.f, 0.f, 0.f};
  for (int rr = 0; rr < TQ; ++rr){
    const float inv = rowinv[rr];
    floatx4* dst = reinterpret_cast<floatx4*>(attnp + ((size_t)bh * SEQ + (q0 + rr)) * SEQ);
    #pragma unroll
    for (int it = 0; it < SEQ / 4 / 256; ++it){
      int j4 = it * 256 + tid;
      floatx4 v = zero4;
      if (j4 >= jz0 && j4 < jz1){
        floatx4 p = *reinterpret_cast<const floatx4*>(&Ss[rr][j4 * 4 - c0]);
        v = (floatx4){p[0] * inv, p[1] * inv, p[2] * inv, p[3] * inv};
      }
      __builtin_nontemporal_store(v, &dst[j4]);
    }
  }

  // PV: wave w handles rows w*4..w*4+3, lane = output dim d
  const int w = tid >> 6;
  const int d = tid & 63;
  float acc[4] = {0.f, 0.f, 0.f, 0.f};
  for (int j = 0; j < nc; ++j){
    float v = __uint_as_float((uint32_t)Vg[((size_t)(c0 + j)) * HDIM + d] << 16);
    #pragma unroll
    for (int i = 0; i < 4; ++i) acc[i] += Ss[w*4 + i][j] * v;
  }
  const int b = bh >> 4, h = bh & 15;
  #pragma unroll
  for (int i = 0; i < 4; ++i){
    int qq = q0 + w*4 + i;
    float val = acc[i] * rowinv[w*4 + i];
    ao[((size_t)(b * SEQ + qq)) * EMBED + h * HDIM + d] = f2bf(val);
  }
}

extern "C" void kernel_launch(void* const* d_in, const int* in_sizes, int n_in,
                              void* d_out, int out_size, void* d_ws, size_t ws_size,
                              hipStream_t stream)
{
  const float* x  = (const float*)d_in[0];
  const float* Wq = (const float*)d_in[1];
  const float* bq = (const float*)d_in[2];
  const float* Wk = (const float*)d_in[3];
  const float* bk = (const float*)d_in[4];
  const float* Wv = (const float*)d_in[5];
  const float* bv = (const float*)d_in[6];
  const float* Wo = (const float*)d_in[7];
  const float* bo = (const float*)d_in[8];

  char* ws = (char*)d_ws;
  ushort* xb   = (ushort*)(ws);                 // x bf16           [4096][1024]
  ushort* wqkv = (ushort*)(ws + 8388608);       // Wq|Wk|Wv bf16    [3072][1024]
  ushort* wo   = (ushort*)(ws + 14680064);      // Wo bf16          [1024][1024]
  ushort* Qb   = (ushort*)(ws + 16777216);      // Q bf16 [b,h,s,d]
  ushort* Kb   = (ushort*)(ws + 25165824);      // K bf16
  ushort* Vb   = (ushort*)(ws + 33554432);      // V bf16
  ushort* ao   = (ushort*)(ws + 41943040);      // attn out bf16 [b,s,e]

  float* outp  = (float*)d_out;                           // [2,2048,1024]
  float* attnp = outp + (size_t)MTOT * EMBED;             // [2,16,2048,2048]

  cast_f32_bf16<<<4096, 256, 0, stream>>>(x,  xb,             4194304);
  cast_f32_bf16<<<1024, 256, 0, stream>>>(Wq, wqkv,           1048576);
  cast_f32_bf16<<<1024, 256, 0, stream>>>(Wk, wqkv + 1048576, 1048576);
  cast_f32_bf16<<<1024, 256, 0, stream>>>(Wv, wqkv + 2097152, 1048576);
  cast_f32_bf16<<<1024, 256, 0, stream>>>(Wo, wo,             1048576);

  gemm_qkv<<<dim3(32, 24), 256, 0, stream>>>(xb, wqkv, bq, bk, bv, Qb, Kb, Vb);
  attn_kernel<<<dim3(128, 32), 256, 0, stream>>>(Qb, Kb, Vb, attnp, ao);
  gemm_out<<<dim3(32, 8), 256, 0, stream>>>(ao, wo, bo, outp);
}

// Round 5
// 183.302 us; speedup vs baseline: 2.1992x; 1.7286x over previous
//
#include <hip/hip_runtime.h>
#include <hip/hip_bf16.h>
#include <stdint.h>

#define EMBED 1024
#define HEADS 16
#define HDIM 64
#define SEQ 2048
#define BATCH 2
#define MTOT (BATCH*SEQ)   // 4096
#define KDIM EMBED         // 1024
#define HALFW 128

typedef __attribute__((ext_vector_type(8))) short short8;
typedef __attribute__((ext_vector_type(4))) float floatx4;

__device__ __forceinline__ ushort f2bf(float f){
  uint32_t x = __float_as_uint(f);
  x += 0x7fffu + ((x >> 16) & 1u);   // RNE
  return (ushort)(x >> 16);
}

__device__ __forceinline__ void gload16(const ushort* g, ushort* l){
  __builtin_amdgcn_global_load_lds(
      (__attribute__((address_space(1))) void*)(void*)g,
      (__attribute__((address_space(3))) void*)l, 16, 0, 0);
}

// ---------------- fused casts f32 -> bf16 (x, Wq, Wk, Wv, Wo) ----------------
__global__ void cast_all(const float* __restrict__ x,  ushort* __restrict__ xb,
                         const float* __restrict__ Wq, const float* __restrict__ Wk,
                         const float* __restrict__ Wv, ushort* __restrict__ wqkv,
                         const float* __restrict__ Wo, ushort* __restrict__ wo)
{
  int bid = blockIdx.x;
  const float* src; ushort* dst; int base;
  if (bid < 4096){ src = x;  dst = xb;   base = bid; }
  else {
    int seg = (bid - 4096) >> 10;            // 0..3
    int sb  = (bid - 4096) & 1023;
    base = sb;
    if      (seg == 0){ src = Wq; dst = wqkv;           }
    else if (seg == 1){ src = Wk; dst = wqkv + 1048576; }
    else if (seg == 2){ src = Wv; dst = wqkv + 2097152; }
    else              { src = Wo; dst = wo;             }
  }
  int i = (base * 256 + threadIdx.x) * 4;
  float4 v = *reinterpret_cast<const float4*>(src + i);
  ushort4 o;
  o.x = f2bf(v.x); o.y = f2bf(v.y); o.z = f2bf(v.z); o.w = f2bf(v.w);
  *reinterpret_cast<ushort4*>(dst + i) = o;
}

// ---------------- QKV GEMM: y = x @ W^T + b, write Q/K/V in [b,h,s,d] bf16 ----------------
__global__ __launch_bounds__(256) void gemm_qkv(
    const ushort* __restrict__ A, const ushort* __restrict__ Bw,
    const float* __restrict__ biasq, const float* __restrict__ biask, const float* __restrict__ biasv,
    ushort* __restrict__ Qo, ushort* __restrict__ Ko, ushort* __restrict__ Vo)
{
  constexpr int BM = 128, BN = 128, BK = 32;
  __shared__ __attribute__((aligned(16))) ushort As[BM*BK];
  __shared__ __attribute__((aligned(16))) ushort Bs[BN*BK];
  const int tid  = threadIdx.x;
  const int lane = tid & 63;
  const int wid  = tid >> 6;
  const int wr = wid >> 1, wc = wid & 1;
  const int m0 = blockIdx.x * BM;
  const int n0 = blockIdx.y * BN;

  floatx4 acc[4][4];
  #pragma unroll
  for (int i = 0; i < 4; ++i)
    #pragma unroll
    for (int j = 0; j < 4; ++j) acc[i][j] = (floatx4){0.f, 0.f, 0.f, 0.f};

  for (int kk = 0; kk < KDIM; kk += BK){
    if (kk) __syncthreads();
    #pragma unroll
    for (int rep = 0; rep < 2; ++rep){
      int cc = tid + rep * 256;             // chunk id 0..511, 8 bf16 each
      int row = cc >> 2, off = (cc & 3) * 8;
      gload16(A  + (size_t)(m0 + row) * KDIM + kk + off, &As[cc * 8]);
      gload16(Bw + (size_t)(n0 + row) * KDIM + kk + off, &Bs[cc * 8]);
    }
    __syncthreads();

    short8 af[4], bfr[4];
    const int rsel = lane & 15, ksel = (lane >> 4) * 8;
    #pragma unroll
    for (int m = 0; m < 4; ++m)
      af[m] = *reinterpret_cast<const short8*>(&As[(wr*64 + m*16 + rsel) * BK + ksel]);
    #pragma unroll
    for (int n = 0; n < 4; ++n)
      bfr[n] = *reinterpret_cast<const short8*>(&Bs[(wc*64 + n*16 + rsel) * BK + ksel]);
    #pragma unroll
    for (int m = 0; m < 4; ++m)
      #pragma unroll
      for (int n = 0; n < 4; ++n)
        acc[m][n] = __builtin_amdgcn_mfma_f32_16x16x32_bf16(af[m], bfr[n], acc[m][n], 0, 0, 0);
  }

  const int which = n0 >> 10;   // uniform per block (128 | 1024)
  const float* bias = (which == 0) ? biasq : ((which == 1) ? biask : biasv);
  ushort* dst = (which == 0) ? Qo : ((which == 1) ? Ko : Vo);
  const int nb = n0 & 1023;
  #pragma unroll
  for (int m = 0; m < 4; ++m)
    #pragma unroll
    for (int n = 0; n < 4; ++n)
      #pragma unroll
      for (int r = 0; r < 4; ++r){
        int mg = m0 + wr*64 + m*16 + (lane >> 4)*4 + r;   // 0..4095
        int ng = nb + wc*64 + n*16 + (lane & 15);          // 0..1023
        float v = acc[m][n][r] + bias[ng];
        int b = mg >> 11, s = mg & (SEQ - 1);
        int h = ng >> 6,  d = ng & 63;
        dst[(((size_t)(b*HEADS + h))*SEQ + s)*HDIM + d] = f2bf(v);
      }
}

// ---------------- V transpose: [b,h,s,d] -> [b,h,d,s] ----------------
__global__ __launch_bounds__(256) void transposeV(const ushort* __restrict__ V,
                                                  ushort* __restrict__ Vt)
{
  __shared__ ushort t[64][72];
  const int tid = threadIdx.x;
  const int bh = blockIdx.y;
  const int s0 = blockIdx.x * 64;
  #pragma unroll
  for (int it = 0; it < 2; ++it){
    int idx = it * 256 + tid;            // 0..511
    int row = idx >> 3, off = (idx & 7) * 8;
    *reinterpret_cast<uint4*>(&t[row][off]) =
        *reinterpret_cast<const uint4*>(V + ((size_t)bh * SEQ + s0 + row) * HDIM + off);
  }
  __syncthreads();
  #pragma unroll
  for (int it = 0; it < 2; ++it){
    int idx = it * 256 + tid;
    int d = idx >> 3, soff = (idx & 7) * 8;
    short8 v;
    #pragma unroll
    for (int e = 0; e < 8; ++e) v[e] = (short)t[soff + e][d];
    *reinterpret_cast<short8*>(Vt + ((size_t)bh * HDIM + d) * SEQ + s0 + soff) = v;
  }
}

// ---------------- output GEMM: out = ao @ Wo^T + bo (fp32 out) ----------------
__global__ __launch_bounds__(256) void gemm_out(
    const ushort* __restrict__ A, const ushort* __restrict__ Bw,
    const float* __restrict__ bias, float* __restrict__ Co)
{
  constexpr int BM = 128, BN = 128, BK = 32;
  __shared__ __attribute__((aligned(16))) ushort As[BM*BK];
  __shared__ __attribute__((aligned(16))) ushort Bs[BN*BK];
  const int tid  = threadIdx.x;
  const int lane = tid & 63;
  const int wid  = tid >> 6;
  const int wr = wid >> 1, wc = wid & 1;
  const int m0 = blockIdx.x * BM;
  const int n0 = blockIdx.y * BN;

  floatx4 acc[4][4];
  #pragma unroll
  for (int i = 0; i < 4; ++i)
    #pragma unroll
    for (int j = 0; j < 4; ++j) acc[i][j] = (floatx4){0.f, 0.f, 0.f, 0.f};

  for (int kk = 0; kk < KDIM; kk += BK){
    if (kk) __syncthreads();
    #pragma unroll
    for (int rep = 0; rep < 2; ++rep){
      int cc = tid + rep * 256;
      int row = cc >> 2, off = (cc & 3) * 8;
      gload16(A  + (size_t)(m0 + row) * KDIM + kk + off, &As[cc * 8]);
      gload16(Bw + (size_t)(n0 + row) * KDIM + kk + off, &Bs[cc * 8]);
    }
    __syncthreads();

    short8 af[4], bfr[4];
    const int rsel = lane & 15, ksel = (lane >> 4) * 8;
    #pragma unroll
    for (int m = 0; m < 4; ++m)
      af[m] = *reinterpret_cast<const short8*>(&As[(wr*64 + m*16 + rsel) * BK + ksel]);
    #pragma unroll
    for (int n = 0; n < 4; ++n)
      bfr[n] = *reinterpret_cast<const short8*>(&Bs[(wc*64 + n*16 + rsel) * BK + ksel]);
    #pragma unroll
    for (int m = 0; m < 4; ++m)
      #pragma unroll
      for (int n = 0; n < 4; ++n)
        acc[m][n] = __builtin_amdgcn_mfma_f32_16x16x32_bf16(af[m], bfr[n], acc[m][n], 0, 0, 0);
  }

  #pragma unroll
  for (int m = 0; m < 4; ++m)
    #pragma unroll
    for (int n = 0; n < 4; ++n)
      #pragma unroll
      for (int r = 0; r < 4; ++r){
        int mg = m0 + wr*64 + m*16 + (lane >> 4)*4 + r;
        int ng = n0 + wc*64 + n*16 + (lane & 15);
        Co[(size_t)mg * EMBED + ng] = acc[m][n][r] + bias[ng];
      }
}

// ---------------- local attention: MFMA scores + softmax + full-row write + MFMA PV ----------------
// Q,K in [b,h,s,d] bf16; V transposed [b,h,d,s] bf16. No K/V/Q LDS staging:
// fragments load straight from global (L2/L3-resident windows).
__global__ __launch_bounds__(256) void attn_kernel(
    const ushort* __restrict__ Qb, const ushort* __restrict__ Kb, const ushort* __restrict__ Vt,
    float* __restrict__ attnp, ushort* __restrict__ ao)
{
  constexpr int TQ = 16;
  constexpr int SPAD = 292;   // f32 stride (292%32==4 -> ~2-way banks)
  constexpr int PPAD = 296;   // ushort stride (148%32==20 -> 2-way banks on b128)
  __shared__ __attribute__((aligned(16))) float  Ss[TQ][SPAD];
  __shared__ __attribute__((aligned(16))) ushort Pb[TQ][PPAD];
  __shared__ float rowinv[TQ];

  const int tid  = threadIdx.x;
  const int lane = tid & 63;
  const int w    = tid >> 6;      // wave 0..3
  const int l15  = lane & 15;
  const int lhi  = lane >> 4;     // 0..3
  const int qt = blockIdx.x;      // 0..127
  const int bh = blockIdx.y;      // 0..31
  const int q0 = qt * TQ;
  const int c0 = max(0, q0 - HALFW);
  const int c1 = min(SEQ, q0 + TQ + HALFW);   // c0,c1 multiples of 16
  const int nc = c1 - c0;                     // 144..272, multiple of 16
  const int ntiles = nc >> 4;
  const int nks = (nc + 31) >> 5;             // 32-key slices for PV

  // ---- scores: S[16q x nc] = Q @ K^T via mfma 16x16x32 ----
  // A-frag (Q): row = l15 (q), k-offset = lhi*8; two k-slices cover D=64
  const ushort* Qrow = Qb + ((size_t)bh * SEQ + q0 + l15) * HDIM + lhi * 8;
  const short8 aq0 = *reinterpret_cast<const short8*>(Qrow);
  const short8 aq1 = *reinterpret_cast<const short8*>(Qrow + 32);

  for (int t = w; t < ntiles; t += 4){
    const ushort* Krow = Kb + ((size_t)bh * SEQ + c0 + t*16 + l15) * HDIM + lhi * 8;
    short8 bk0 = *reinterpret_cast<const short8*>(Krow);
    short8 bk1 = *reinterpret_cast<const short8*>(Krow + 32);
    floatx4 acc = (floatx4){0.f, 0.f, 0.f, 0.f};
    acc = __builtin_amdgcn_mfma_f32_16x16x32_bf16(aq0, bk0, acc, 0, 0, 0);
    acc = __builtin_amdgcn_mfma_f32_16x16x32_bf16(aq1, bk1, acc, 0, 0, 0);
    // C layout: col = l15 (key within tile), row = lhi*4 + r (q-row)
    const int c = c0 + t*16 + l15;
    #pragma unroll
    for (int r = 0; r < 4; ++r){
      int q = q0 + lhi*4 + r;
      float s = (c < q - HALFW || c > q + HALFW) ? -1e30f : acc[r] * 0.125f;
      Ss[lhi*4 + r][t*16 + l15] = s;
    }
  }
  __syncthreads();

  // ---- softmax over row r (16 threads per row, within one wave) ----
  const int r  = tid >> 4;
  const int lc = tid & 15;
  float mx = -1e30f;
  for (int j = lc; j < nc; j += 16) mx = fmaxf(mx, Ss[r][j]);
  #pragma unroll
  for (int o = 1; o < 16; o <<= 1) mx = fmaxf(mx, __shfl_xor(mx, o, 64));
  float sum = 0.f;
  for (int j = lc; j < nc; j += 16){
    float p = __expf(Ss[r][j] - mx);   // masked entries -> exactly 0
    Ss[r][j] = p;
    Pb[r][j] = f2bf(p);
    sum += p;
  }
  for (int j = nc + lc; j < nks * 32; j += 16) Pb[r][j] = 0;  // zero-pad P
  #pragma unroll
  for (int o = 1; o < 16; o <<= 1) sum += __shfl_xor(sum, o, 64);
  if (lc == 0) rowinv[r] = 1.f / sum;
  __syncthreads();

  // ---- full attn rows: zeros outside [c0,c1), p*inv inside ----
  const int jz0 = c0 >> 2, jz1 = c1 >> 2;
  const floatx4 zero4 = (floatx4){0.f, 0.f, 0.f, 0.f};
  for (int rr = 0; rr < TQ; ++rr){
    const float inv = rowinv[rr];
    floatx4* dst = reinterpret_cast<floatx4*>(attnp + ((size_t)bh * SEQ + (q0 + rr)) * SEQ);
    #pragma unroll
    for (int it = 0; it < SEQ / 4 / 256; ++it){
      int j4 = it * 256 + tid;
      floatx4 v = zero4;
      if (j4 >= jz0 && j4 < jz1){
        floatx4 p = *reinterpret_cast<const floatx4*>(&Ss[rr][j4 * 4 - c0]);
        v = (floatx4){p[0] * inv, p[1] * inv, p[2] * inv, p[3] * inv};
      }
      __builtin_nontemporal_store(v, &dst[j4]);
    }
  }

  // ---- PV via mfma: out[16q x 16d-tile] per wave; V from global (transposed) ----
  floatx4 oacc = (floatx4){0.f, 0.f, 0.f, 0.f};
  const ushort* Vrow = Vt + ((size_t)bh * HDIM + w*16 + l15) * SEQ + c0 + lhi * 8;
  for (int ks = 0; ks < nks; ++ks){
    short8 ap = *reinterpret_cast<const short8*>(&Pb[l15][ks*32 + lhi*8]);
    short8 bv = *reinterpret_cast<const short8*>(Vrow + ks*32);
    oacc = __builtin_amdgcn_mfma_f32_16x16x32_bf16(ap, bv, oacc, 0, 0, 0);
  }
  const int b = bh >> 4, h = bh & 15;
  #pragma unroll
  for (int rr = 0; rr < 4; ++rr){
    int q = q0 + lhi*4 + rr;
    float val = oacc[rr] * rowinv[lhi*4 + rr];
    ao[((size_t)(b * SEQ + q)) * EMBED + h * HDIM + w*16 + l15] = f2bf(val);
  }
}

extern "C" void kernel_launch(void* const* d_in, const int* in_sizes, int n_in,
                              void* d_out, int out_size, void* d_ws, size_t ws_size,
                              hipStream_t stream)
{
  const float* x  = (const float*)d_in[0];
  const float* Wq = (const float*)d_in[1];
  const float* bq = (const float*)d_in[2];
  const float* Wk = (const float*)d_in[3];
  const float* bk = (const float*)d_in[4];
  const float* Wv = (const float*)d_in[5];
  const float* bv = (const float*)d_in[6];
  const float* Wo = (const float*)d_in[7];
  const float* bo = (const float*)d_in[8];

  char* ws = (char*)d_ws;
  ushort* xb   = (ushort*)(ws);                 // x bf16 [4096][1024]   (reused as Vt later)
  ushort* wqkv = (ushort*)(ws + 8388608);       // Wq|Wk|Wv bf16
  ushort* wo   = (ushort*)(ws + 14680064);      // Wo bf16
  ushort* Qb   = (ushort*)(ws + 16777216);      // Q bf16 [b,h,s,d]
  ushort* Kb   = (ushort*)(ws + 25165824);      // K bf16 [b,h,s,d]
  ushort* Vb   = (ushort*)(ws + 33554432);      // V bf16 [b,h,s,d]
  ushort* ao   = (ushort*)(ws + 41943040);      // attn out bf16 [b,s,e]
  ushort* Vt   = (ushort*)(ws);                 // V^T bf16 [b,h,d,s] — aliases xb (dead after gemm_qkv)

  float* outp  = (float*)d_out;                           // [2,2048,1024]
  float* attnp = outp + (size_t)MTOT * EMBED;             // [2,16,2048,2048]

  cast_all<<<8192, 256, 0, stream>>>(x, xb, Wq, Wk, Wv, wqkv, Wo, wo);
  gemm_qkv<<<dim3(32, 24), 256, 0, stream>>>(xb, wqkv, bq, bk, bv, Qb, Kb, Vb);
  transposeV<<<dim3(32, 32), 256, 0, stream>>>(Vb, Vt);
  attn_kernel<<<dim3(128, 32), 256, 0, stream>>>(Qb, Kb, Vt, attnp, ao);
  gemm_out<<<dim3(32, 8), 256, 0, stream>>>(ao, wo, bo, outp);
}

// Round 6
// 181.987 us; speedup vs baseline: 2.2151x; 1.0072x over previous
//
#include <hip/hip_runtime.h>
#include <hip/hip_bf16.h>
#include <stdint.h>

#define EMBED 1024
#define HEADS 16
#define HDIM 64
#define SEQ 2048
#define BATCH 2
#define MTOT (BATCH*SEQ)   // 4096
#define KDIM EMBED         // 1024
#define HALFW 128

typedef __attribute__((ext_vector_type(8))) short short8;
typedef __attribute__((ext_vector_type(4))) float floatx4;

__device__ __forceinline__ ushort f2bf(float f){
  uint32_t x = __float_as_uint(f);
  x += 0x7fffu + ((x >> 16) & 1u);   // RNE
  return (ushort)(x >> 16);
}

__device__ __forceinline__ void gload16(const ushort* g, ushort* l){
  __builtin_amdgcn_global_load_lds(
      (__attribute__((address_space(1))) void*)(void*)g,
      (__attribute__((address_space(3))) void*)l, 16, 0, 0);
}

// ---------------- fused casts f32 -> bf16 (x, Wq, Wk, Wv, Wo) ----------------
__global__ void cast_all(const float* __restrict__ x,  ushort* __restrict__ xb,
                         const float* __restrict__ Wq, const float* __restrict__ Wk,
                         const float* __restrict__ Wv, ushort* __restrict__ wqkv,
                         const float* __restrict__ Wo, ushort* __restrict__ wo)
{
  int bid = blockIdx.x;
  const float* src; ushort* dst; int base;
  if (bid < 4096){ src = x;  dst = xb;   base = bid; }
  else {
    int seg = (bid - 4096) >> 10;            // 0..3
    int sb  = (bid - 4096) & 1023;
    base = sb;
    if      (seg == 0){ src = Wq; dst = wqkv;           }
    else if (seg == 1){ src = Wk; dst = wqkv + 1048576; }
    else if (seg == 2){ src = Wv; dst = wqkv + 2097152; }
    else              { src = Wo; dst = wo;             }
  }
  int i = (base * 256 + threadIdx.x) * 4;
  float4 v = *reinterpret_cast<const float4*>(src + i);
  ushort4 o;
  o.x = f2bf(v.x); o.y = f2bf(v.y); o.z = f2bf(v.z); o.w = f2bf(v.w);
  *reinterpret_cast<ushort4*>(dst + i) = o;
}

// ---------------- QKV GEMM: y = x @ W^T + b, write Q/K/V in [b,h,s,d] bf16 ----------------
// 2-phase double-buffered staging (T3-minimum), XCD-swizzled 1D grid (768 blocks).
__global__ __launch_bounds__(256) void gemm_qkv(
    const ushort* __restrict__ A, const ushort* __restrict__ Bw,
    const float* __restrict__ biasq, const float* __restrict__ biask, const float* __restrict__ biasv,
    ushort* __restrict__ Qo, ushort* __restrict__ Ko, ushort* __restrict__ Vo)
{
  constexpr int BM = 128, BN = 128, BK = 32;
  __shared__ __attribute__((aligned(16))) ushort As[2][BM*BK];
  __shared__ __attribute__((aligned(16))) ushort Bs[2][BN*BK];
  const int tid  = threadIdx.x;
  const int lane = tid & 63;
  const int wid  = tid >> 6;
  const int wr = wid >> 1, wc = wid & 1;

  // XCD-aware bijective swizzle: 768 blocks, 96 per XCD
  const int bid = blockIdx.x;
  const int swz = (bid & 7) * 96 + (bid >> 3);
  const int m0 = (swz & 31) * BM;
  const int n0 = (swz >> 5) * BN;

  // staging addresses (two 16B chunks per thread per operand)
  const int cc0 = tid, cc1 = tid + 256;
  const int row0 = cc0 >> 2, off0 = (cc0 & 3) * 8;
  const int row1 = cc1 >> 2, off1 = (cc1 & 3) * 8;
  const ushort* A0 = A  + (size_t)(m0 + row0) * KDIM + off0;
  const ushort* A1 = A  + (size_t)(m0 + row1) * KDIM + off1;
  const ushort* B0 = Bw + (size_t)(n0 + row0) * KDIM + off0;
  const ushort* B1 = Bw + (size_t)(n0 + row1) * KDIM + off1;

  floatx4 acc[4][4];
  #pragma unroll
  for (int i = 0; i < 4; ++i)
    #pragma unroll
    for (int j = 0; j < 4; ++j) acc[i][j] = (floatx4){0.f, 0.f, 0.f, 0.f};

  const int rsel = lane & 15, ksel = (lane >> 4) * 8;

  // prologue: stage K-slice 0 into buf 0
  gload16(A0, &As[0][cc0 * 8]);
  gload16(B0, &Bs[0][cc0 * 8]);
  gload16(A1, &As[0][cc1 * 8]);
  gload16(B1, &Bs[0][cc1 * 8]);
  __syncthreads();

  int cur = 0;
  for (int kk = 0; kk < KDIM; kk += BK){
    if (kk + BK < KDIM){            // prefetch next K-slice into other buffer
      gload16(A0 + kk + BK, &As[cur ^ 1][cc0 * 8]);
      gload16(B0 + kk + BK, &Bs[cur ^ 1][cc0 * 8]);
      gload16(A1 + kk + BK, &As[cur ^ 1][cc1 * 8]);
      gload16(B1 + kk + BK, &Bs[cur ^ 1][cc1 * 8]);
    }
    short8 af[4], bfr[4];
    #pragma unroll
    for (int m = 0; m < 4; ++m)
      af[m] = *reinterpret_cast<const short8*>(&As[cur][(wr*64 + m*16 + rsel) * BK + ksel]);
    #pragma unroll
    for (int n = 0; n < 4; ++n)
      bfr[n] = *reinterpret_cast<const short8*>(&Bs[cur][(wc*64 + n*16 + rsel) * BK + ksel]);
    #pragma unroll
    for (int m = 0; m < 4; ++m)
      #pragma unroll
      for (int n = 0; n < 4; ++n)
        acc[m][n] = __builtin_amdgcn_mfma_f32_16x16x32_bf16(af[m], bfr[n], acc[m][n], 0, 0, 0);
    __syncthreads();                // drains prefetch vmcnt + WAR protection
    cur ^= 1;
  }

  const int which = n0 >> 10;   // uniform per block (128 | 1024)
  const float* bias = (which == 0) ? biasq : ((which == 1) ? biask : biasv);
  ushort* dst = (which == 0) ? Qo : ((which == 1) ? Ko : Vo);
  const int nb = n0 & 1023;
  #pragma unroll
  for (int m = 0; m < 4; ++m)
    #pragma unroll
    for (int n = 0; n < 4; ++n)
      #pragma unroll
      for (int r = 0; r < 4; ++r){
        int mg = m0 + wr*64 + m*16 + (lane >> 4)*4 + r;   // 0..4095
        int ng = nb + wc*64 + n*16 + (lane & 15);          // 0..1023
        float v = acc[m][n][r] + bias[ng];
        int b = mg >> 11, s = mg & (SEQ - 1);
        int h = ng >> 6,  d = ng & 63;
        dst[(((size_t)(b*HEADS + h))*SEQ + s)*HDIM + d] = f2bf(v);
      }
}

// ---------------- V transpose: [b,h,s,d] -> [b,h,d,s] ----------------
__global__ __launch_bounds__(256) void transposeV(const ushort* __restrict__ V,
                                                  ushort* __restrict__ Vt)
{
  __shared__ ushort t[64][72];
  const int tid = threadIdx.x;
  const int bh = blockIdx.y;
  const int s0 = blockIdx.x * 64;
  #pragma unroll
  for (int it = 0; it < 2; ++it){
    int idx = it * 256 + tid;            // 0..511
    int row = idx >> 3, off = (idx & 7) * 8;
    *reinterpret_cast<uint4*>(&t[row][off]) =
        *reinterpret_cast<const uint4*>(V + ((size_t)bh * SEQ + s0 + row) * HDIM + off);
  }
  __syncthreads();
  #pragma unroll
  for (int it = 0; it < 2; ++it){
    int idx = it * 256 + tid;
    int d = idx >> 3, soff = (idx & 7) * 8;
    short8 v;
    #pragma unroll
    for (int e = 0; e < 8; ++e) v[e] = (short)t[soff + e][d];
    *reinterpret_cast<short8*>(Vt + ((size_t)bh * HDIM + d) * SEQ + s0 + soff) = v;
  }
}

// ---------------- output GEMM: out = ao @ Wo^T + bo (fp32 out) ----------------
// Same 2-phase structure; 1D grid 256, XCD-swizzled.
__global__ __launch_bounds__(256) void gemm_out(
    const ushort* __restrict__ A, const ushort* __restrict__ Bw,
    const float* __restrict__ bias, float* __restrict__ Co)
{
  constexpr int BM = 128, BN = 128, BK = 32;
  __shared__ __attribute__((aligned(16))) ushort As[2][BM*BK];
  __shared__ __attribute__((aligned(16))) ushort Bs[2][BN*BK];
  const int tid  = threadIdx.x;
  const int lane = tid & 63;
  const int wid  = tid >> 6;
  const int wr = wid >> 1, wc = wid & 1;

  const int bid = blockIdx.x;                 // 256 blocks, 32 per XCD
  const int swz = (bid & 7) * 32 + (bid >> 3);
  const int m0 = (swz & 31) * BM;
  const int n0 = (swz >> 5) * BN;

  const int cc0 = tid, cc1 = tid + 256;
  const int row0 = cc0 >> 2, off0 = (cc0 & 3) * 8;
  const int row1 = cc1 >> 2, off1 = (cc1 & 3) * 8;
  const ushort* A0 = A  + (size_t)(m0 + row0) * KDIM + off0;
  const ushort* A1 = A  + (size_t)(m0 + row1) * KDIM + off1;
  const ushort* B0 = Bw + (size_t)(n0 + row0) * KDIM + off0;
  const ushort* B1 = Bw + (size_t)(n0 + row1) * KDIM + off1;

  floatx4 acc[4][4];
  #pragma unroll
  for (int i = 0; i < 4; ++i)
    #pragma unroll
    for (int j = 0; j < 4; ++j) acc[i][j] = (floatx4){0.f, 0.f, 0.f, 0.f};

  const int rsel = lane & 15, ksel = (lane >> 4) * 8;

  gload16(A0, &As[0][cc0 * 8]);
  gload16(B0, &Bs[0][cc0 * 8]);
  gload16(A1, &As[0][cc1 * 8]);
  gload16(B1, &Bs[0][cc1 * 8]);
  __syncthreads();

  int cur = 0;
  for (int kk = 0; kk < KDIM; kk += BK){
    if (kk + BK < KDIM){
      gload16(A0 + kk + BK, &As[cur ^ 1][cc0 * 8]);
      gload16(B0 + kk + BK, &Bs[cur ^ 1][cc0 * 8]);
      gload16(A1 + kk + BK, &As[cur ^ 1][cc1 * 8]);
      gload16(B1 + kk + BK, &Bs[cur ^ 1][cc1 * 8]);
    }
    short8 af[4], bfr[4];
    #pragma unroll
    for (int m = 0; m < 4; ++m)
      af[m] = *reinterpret_cast<const short8*>(&As[cur][(wr*64 + m*16 + rsel) * BK + ksel]);
    #pragma unroll
    for (int n = 0; n < 4; ++n)
      bfr[n] = *reinterpret_cast<const short8*>(&Bs[cur][(wc*64 + n*16 + rsel) * BK + ksel]);
    #pragma unroll
    for (int m = 0; m < 4; ++m)
      #pragma unroll
      for (int n = 0; n < 4; ++n)
        acc[m][n] = __builtin_amdgcn_mfma_f32_16x16x32_bf16(af[m], bfr[n], acc[m][n], 0, 0, 0);
    __syncthreads();
    cur ^= 1;
  }

  #pragma unroll
  for (int m = 0; m < 4; ++m)
    #pragma unroll
    for (int n = 0; n < 4; ++n)
      #pragma unroll
      for (int r = 0; r < 4; ++r){
        int mg = m0 + wr*64 + m*16 + (lane >> 4)*4 + r;
        int ng = n0 + wc*64 + n*16 + (lane & 15);
        Co[(size_t)mg * EMBED + ng] = acc[m][n][r] + bias[ng];
      }
}

// ---------------- local attention: MFMA scores + softmax + full-row write + MFMA PV ----------------
// Q,K in [b,h,s,d] bf16; V transposed [b,h,d,s] bf16. No K/V/Q LDS staging:
// fragments load straight from global (L2/L3-resident windows).
__global__ __launch_bounds__(256) void attn_kernel(
    const ushort* __restrict__ Qb, const ushort* __restrict__ Kb, const ushort* __restrict__ Vt,
    float* __restrict__ attnp, ushort* __restrict__ ao)
{
  constexpr int TQ = 16;
  constexpr int SPAD = 292;   // f32 stride (292%32==4 -> ~2-way banks)
  constexpr int PPAD = 296;   // ushort stride
  __shared__ __attribute__((aligned(16))) float  Ss[TQ][SPAD];
  __shared__ __attribute__((aligned(16))) ushort Pb[TQ][PPAD];
  __shared__ float rowinv[TQ];

  const int tid  = threadIdx.x;
  const int lane = tid & 63;
  const int w    = tid >> 6;      // wave 0..3
  const int l15  = lane & 15;
  const int lhi  = lane >> 4;     // 0..3
  const int qt = blockIdx.x;      // 0..127
  const int bh = blockIdx.y;      // 0..31
  const int q0 = qt * TQ;
  const int c0 = max(0, q0 - HALFW);
  const int c1 = min(SEQ, q0 + TQ + HALFW);   // c0,c1 multiples of 16
  const int nc = c1 - c0;                     // 144..272, multiple of 16
  const int ntiles = nc >> 4;
  const int nks = (nc + 31) >> 5;             // 32-key slices for PV

  // ---- scores: S[16q x nc] = Q @ K^T via mfma 16x16x32 ----
  const ushort* Qrow = Qb + ((size_t)bh * SEQ + q0 + l15) * HDIM + lhi * 8;
  const short8 aq0 = *reinterpret_cast<const short8*>(Qrow);
  const short8 aq1 = *reinterpret_cast<const short8*>(Qrow + 32);

  for (int t = w; t < ntiles; t += 4){
    const ushort* Krow = Kb + ((size_t)bh * SEQ + c0 + t*16 + l15) * HDIM + lhi * 8;
    short8 bk0 = *reinterpret_cast<const short8*>(Krow);
    short8 bk1 = *reinterpret_cast<const short8*>(Krow + 32);
    floatx4 acc = (floatx4){0.f, 0.f, 0.f, 0.f};
    acc = __builtin_amdgcn_mfma_f32_16x16x32_bf16(aq0, bk0, acc, 0, 0, 0);
    acc = __builtin_amdgcn_mfma_f32_16x16x32_bf16(aq1, bk1, acc, 0, 0, 0);
    const int c = c0 + t*16 + l15;
    #pragma unroll
    for (int r = 0; r < 4; ++r){
      int q = q0 + lhi*4 + r;
      float s = (c < q - HALFW || c > q + HALFW) ? -1e30f : acc[r] * 0.125f;
      Ss[lhi*4 + r][t*16 + l15] = s;
    }
  }
  __syncthreads();

  // ---- softmax over row r (16 threads per row, within one wave) ----
  const int r  = tid >> 4;
  const int lc = tid & 15;
  float mx = -1e30f;
  for (int j = lc; j < nc; j += 16) mx = fmaxf(mx, Ss[r][j]);
  #pragma unroll
  for (int o = 1; o < 16; o <<= 1) mx = fmaxf(mx, __shfl_xor(mx, o, 64));
  float sum = 0.f;
  for (int j = lc; j < nc; j += 16){
    float p = __expf(Ss[r][j] - mx);   // masked entries -> exactly 0
    Ss[r][j] = p;
    Pb[r][j] = f2bf(p);
    sum += p;
  }
  for (int j = nc + lc; j < nks * 32; j += 16) Pb[r][j] = 0;  // zero-pad P
  #pragma unroll
  for (int o = 1; o < 16; o <<= 1) sum += __shfl_xor(sum, o, 64);
  if (lc == 0) rowinv[r] = 1.f / sum;
  __syncthreads();

  // ---- full attn rows: zeros outside [c0,c1), p*inv inside ----
  const int jz0 = c0 >> 2, jz1 = c1 >> 2;
  const floatx4 zero4 = (floatx4){0.f, 0.f, 0.f, 0.f};
  for (int rr = 0; rr < TQ; ++rr){
    const float inv = rowinv[rr];
    floatx4* dst = reinterpret_cast<floatx4*>(attnp + ((size_t)bh * SEQ + (q0 + rr)) * SEQ);
    #pragma unroll
    for (int it = 0; it < SEQ / 4 / 256; ++it){
      int j4 = it * 256 + tid;
      floatx4 v = zero4;
      if (j4 >= jz0 && j4 < jz1){
        floatx4 p = *reinterpret_cast<const floatx4*>(&Ss[rr][j4 * 4 - c0]);
        v = (floatx4){p[0] * inv, p[1] * inv, p[2] * inv, p[3] * inv};
      }
      __builtin_nontemporal_store(v, &dst[j4]);
    }
  }

  // ---- PV via mfma: out[16q x 16d-tile] per wave; V from global (transposed) ----
  floatx4 oacc = (floatx4){0.f, 0.f, 0.f, 0.f};
  const ushort* Vrow = Vt + ((size_t)bh * HDIM + w*16 + l15) * SEQ + c0 + lhi * 8;
  for (int ks = 0; ks < nks; ++ks){
    short8 ap = *reinterpret_cast<const short8*>(&Pb[l15][ks*32 + lhi*8]);
    short8 bv = *reinterpret_cast<const short8*>(Vrow + ks*32);
    oacc = __builtin_amdgcn_mfma_f32_16x16x32_bf16(ap, bv, oacc, 0, 0, 0);
  }
  const int b = bh >> 4, h = bh & 15;
  #pragma unroll
  for (int rr = 0; rr < 4; ++rr){
    int q = q0 + lhi*4 + rr;
    float val = oacc[rr] * rowinv[lhi*4 + rr];
    ao[((size_t)(b * SEQ + q)) * EMBED + h * HDIM + w*16 + l15] = f2bf(val);
  }
}

extern "C" void kernel_launch(void* const* d_in, const int* in_sizes, int n_in,
                              void* d_out, int out_size, void* d_ws, size_t ws_size,
                              hipStream_t stream)
{
  const float* x  = (const float*)d_in[0];
  const float* Wq = (const float*)d_in[1];
  const float* bq = (const float*)d_in[2];
  const float* Wk = (const float*)d_in[3];
  const float* bk = (const float*)d_in[4];
  const float* Wv = (const float*)d_in[5];
  const float* bv = (const float*)d_in[6];
  const float* Wo = (const float*)d_in[7];
  const float* bo = (const float*)d_in[8];

  char* ws = (char*)d_ws;
  ushort* xb   = (ushort*)(ws);                 // x bf16 [4096][1024]   (reused as Vt later)
  ushort* wqkv = (ushort*)(ws + 8388608);       // Wq|Wk|Wv bf16
  ushort* wo   = (ushort*)(ws + 14680064);      // Wo bf16
  ushort* Qb   = (ushort*)(ws + 16777216);      // Q bf16 [b,h,s,d]
  ushort* Kb   = (ushort*)(ws + 25165824);      // K bf16 [b,h,s,d]
  ushort* Vb   = (ushort*)(ws + 33554432);      // V bf16 [b,h,s,d]
  ushort* ao   = (ushort*)(ws + 41943040);      // attn out bf16 [b,s,e]
  ushort* Vt   = (ushort*)(ws);                 // V^T bf16 [b,h,d,s] — aliases xb (dead after gemm_qkv)

  float* outp  = (float*)d_out;                           // [2,2048,1024]
  float* attnp = outp + (size_t)MTOT * EMBED;             // [2,16,2048,2048]

  cast_all<<<8192, 256, 0, stream>>>(x, xb, Wq, Wk, Wv, wqkv, Wo, wo);
  gemm_qkv<<<768, 256, 0, stream>>>(xb, wqkv, bq, bk, bv, Qb, Kb, Vb);
  transposeV<<<dim3(32, 32), 256, 0, stream>>>(Vb, Vt);
  attn_kernel<<<dim3(128, 32), 256, 0, stream>>>(Qb, Kb, Vt, attnp, ao);
  gemm_out<<<256, 256, 0, stream>>>(ao, wo, bo, outp);
}